// Round 5
// baseline (2565.087 us; speedup 1.0000x reference)
//
#include <hip/hip_runtime.h>
#include <math.h>

#define NROWS 16384
#define T 512
#define NRI 1024
#define LAYERS 16
#define NBLK 256

typedef _Float16 f16;
typedef _Float16 half8 __attribute__((ext_vector_type(8)));
typedef float floatx4 __attribute__((ext_vector_type(4)));

// ws float offsets
#define OFF_PMAX 0                       // 256
#define OFF_SCALE 256                    // [0]=5/max, [1]=max/5
#define OFF_BAR 260                      // 2 uints (count, generation)
#define OFF_SUMS 512                     // LAYERS*NRI per-col |R|^2 sums
#define OFF_W1H (OFF_SUMS + LAYERS*NRI)  // 98304 f16, frag-chunk-linear
#define OFF_W2H (OFF_W1H + 49152)        // 98304 f16

__global__ void kmax(const float* __restrict__ u, float* __restrict__ pmax, int n) {
    __shared__ float sm[256];
    float m = -1e30f;
    for (int i = blockIdx.x * blockDim.x + threadIdx.x; i < n; i += gridDim.x * blockDim.x)
        m = fmaxf(m, u[i]);
    sm[threadIdx.x] = m;
    __syncthreads();
    for (int s = 128; s > 0; s >>= 1) {
        if (threadIdx.x < s) sm[threadIdx.x] = fmaxf(sm[threadIdx.x], sm[threadIdx.x + s]);
        __syncthreads();
    }
    if (threadIdx.x == 0) pmax[blockIdx.x] = sm[0];
}

__global__ void kinit(float* __restrict__ ws) {
    __shared__ float sm[256];
    int t = threadIdx.x;
    sm[t] = ws[OFF_PMAX + t];
    __syncthreads();
    for (int s = 128; s > 0; s >>= 1) {
        if (t < s) sm[t] = fmaxf(sm[t], sm[t + s]);
        __syncthreads();
    }
    if (t == 0) {
        float m = fabsf(sm[0]);
        ws[OFF_SCALE]     = 5.0f / m;
        ws[OFF_SCALE + 1] = m / 5.0f;
    }
    if (t < 2) ((unsigned*)(ws + OFF_BAR))[t] = 0u;
    for (int i = t; i < LAYERS * NRI; i += 256) ws[OFF_SUMS + i] = 0.0f;
}

// Weight tables, f16, fragment-chunk-linear (identical to validated R3 layout).
__global__ void kwf(float* __restrict__ ws) {
    int idx = blockIdx.x * 256 + threadIdx.x;
    if (idx >= 2 * 98304) return;
    int which = idx >= 98304;
    int id = which ? idx - 98304 : idx;
    int j = id & 7, lane = (id >> 3) & 63, r = id >> 9;
    int k, n, t, f, q, e;
    if (!which) {
        int kc = r % 3, r2 = r / 3, nt8 = r2 & 7, c = r2 >> 3;
        k = kc * 32 + (lane >> 4) * 8 + j;
        n = c * 128 + nt8 * 16 + (lane & 15);
        f = k >> 1; q = k & 1; t = n >> 1; e = n & 1;
    } else {
        int nt = r % 6, r2 = r / 6, kc = r2 & 3, ch = r2 >> 2;
        k = ch * 128 + kc * 32 + (lane >> 4) * 8 + j;
        n = nt * 16 + (lane & 15);
        t = k >> 1; q = k & 1; f = n >> 1; e = n & 1;
    }
    int ft = (f * t) & (T - 1);
    float sv, cv;
    sincosf((float)ft * 0.012271846303085129f, &sv, &cv);
    const float sc = 0.04419417382415922f;
    cv *= sc; sv *= sc;
    float val;
    if (!which) val = (e == 0) ? (q == 0 ? cv : -sv) : (q == 0 ?  sv : cv);
    else        val = (e == 0) ? (q == 0 ? cv :  sv) : (q == 0 ? -sv : cv);
    f16* dst = (f16*)(ws + (which ? OFF_W2H : OFF_W1H));
    dst[id] = (f16)val;
}

__device__ __forceinline__ void gridbar(unsigned* bar) {
    __syncthreads();
    if (threadIdx.x == 0) {
        unsigned gen = __hip_atomic_load(&bar[1], __ATOMIC_RELAXED, __HIP_MEMORY_SCOPE_AGENT);
        unsigned a = __hip_atomic_fetch_add(&bar[0], 1u, __ATOMIC_ACQ_REL, __HIP_MEMORY_SCOPE_AGENT);
        if (a + 1 == NBLK) {
            __hip_atomic_store(&bar[0], 0u, __ATOMIC_RELAXED, __HIP_MEMORY_SCOPE_AGENT);
            __hip_atomic_fetch_add(&bar[1], 1u, __ATOMIC_RELEASE, __HIP_MEMORY_SCOPE_AGENT);
        } else {
            while (__hip_atomic_load(&bar[1], __ATOMIC_ACQUIRE, __HIP_MEMORY_SCOPE_AGENT) == gen)
                __builtin_amdgcn_s_sleep(8);
        }
    }
    __syncthreads();
}

// Persistent kernel: R ([64 rows x 1024 cols] per block) lives in registers
// across all 16 layers. 4 waves x 16 rows. 1 block/CU, 256 blocks.
__global__ __launch_bounds__(256) void P(const float* __restrict__ u, float* __restrict__ ws,
                                         const float* __restrict__ S1, const float* __restrict__ S2,
                                         float* __restrict__ out) {
    __shared__ f16 wbuf[3][12288];        // 72 KB triple-buffered weight chunks
    __shared__ float usb[6144];           // 24 KB scaled u tile [row][fc]
    __shared__ float garr[NRI];           // 4 KB current gate
    __shared__ float lsum[NRI];           // 4 KB block-local |R|^2 partials
    __shared__ float trw[4][1632];        // 26 KB per-wave transpose scratch (17-pad)

    const int tid = threadIdx.x;
    const int wv = tid >> 6;
    const int lane = tid & 63;
    const int quad = lane >> 4;
    const int l15 = lane & 15;
    const int m0 = blockIdx.x * 64;

    unsigned* bar = (unsigned*)(ws + OFF_BAR);
    float* __restrict__ sums = ws + OFF_SUMS;
    const float4* __restrict__ w1 = (const float4*)(ws + OFF_W1H);
    const float4* __restrict__ w2 = (const float4*)(ws + OFF_W2H);
    const float s5 = ws[OFF_SCALE];
    const float is = ws[OFF_SCALE + 1];
    const float s1v = S1[0], s2v = S2[0];
    float* __restrict__ trz = trw[wv];

    for (int i = tid; i < 6144; i += 256) usb[i] = s5 * u[(size_t)m0 * 96 + i];
    for (int i = tid; i < NRI; i += 256) lsum[i] = 0.0f;
    __syncthreads();

    floatx4 R[64];

    for (int l = 0; l < LAYERS; l++) {
        const int first = (l == 0);
        const int last = (l == LAYERS - 1);

        // ---------- phase Z: R = (first ? 0 : g_{l-1} o R) + z x W1 ; lsum ----------
        {
            half8 Ah[3], Al[3];
#pragma unroll
            for (int kc = 0; kc < 3; kc++) {
#pragma unroll
                for (int j = 0; j < 8; j++) {
                    int k = kc * 32 + quad * 8 + j;
                    float v = first ? usb[(wv * 16 + l15) * 96 + k] : trz[k * 17 + l15];
                    f16 h = (f16)v;
                    Ah[kc][j] = h;
                    Al[kc][j] = (f16)(v - (float)h);
                }
            }
            float4 pr[2][6];
#pragma unroll
            for (int s = 0; s < 6; s++) pr[0][s] = w1[s * 256 + tid];
            {
                float4* db = (float4*)&wbuf[0][0];
#pragma unroll
                for (int s = 0; s < 6; s++) db[s * 256 + tid] = pr[0][s];
            }
#pragma unroll
            for (int s = 0; s < 6; s++) pr[1][s] = w1[1536 + s * 256 + tid];
            __syncthreads();
#pragma unroll
            for (int ch = 0; ch < 8; ch++) {
                if (ch < 7) {
                    float4* db = (float4*)&wbuf[(ch + 1) % 3][0];
#pragma unroll
                    for (int s = 0; s < 6; s++) db[s * 256 + tid] = pr[(ch + 1) & 1][s];
                }
                if (ch < 6) {
#pragma unroll
                    for (int s = 0; s < 6; s++) pr[ch & 1][s] = w1[(ch + 2) * 1536 + s * 256 + tid];
                }
                __syncthreads();
                const f16* wb = &wbuf[ch % 3][0];
#pragma unroll
                for (int nt = 0; nt < 8; nt++) {
                    const int ti = ch * 8 + nt;
                    floatx4 acc;
                    if (first) acc = (floatx4){0.f, 0.f, 0.f, 0.f};
                    else {
                        float g = garr[ti * 16 + l15];
                        acc = g * R[ti];
                    }
#pragma unroll
                    for (int kc = 0; kc < 3; kc++) {
                        half8 Bv = *(const half8*)(wb + ((nt * 3 + kc) * 64 + lane) * 8);
                        acc = __builtin_amdgcn_mfma_f32_16x16x32_f16(Ah[kc], Bv, acc, 0, 0, 0);
                        acc = __builtin_amdgcn_mfma_f32_16x16x32_f16(Al[kc], Bv, acc, 0, 0, 0);
                    }
                    R[ti] = acc;
                    float cs = acc[0] * acc[0] + acc[1] * acc[1] + acc[2] * acc[2] + acc[3] * acc[3];
                    cs += __shfl_xor(cs, 16, 64);
                    cs += __shfl_xor(cs, 32, 64);
                    if (lane < 16) atomicAdd(&lsum[ti * 16 + lane], cs);
                }
            }
        }

        // ---------- sums flush + grid barrier + gate ----------
        __syncthreads();
        for (int i = tid; i < NRI; i += 256) atomicAdd(&sums[l * NRI + i], lsum[i]);
        __threadfence();
        gridbar(bar);
        for (int t = tid; t < 512; t += 256) {
            float sa = __hip_atomic_load(&sums[l * NRI + 2 * t], __ATOMIC_RELAXED, __HIP_MEMORY_SCOPE_AGENT);
            float sb = __hip_atomic_load(&sums[l * NRI + 2 * t + 1], __ATOMIC_RELAXED, __HIP_MEMORY_SCOPE_AGENT);
            float rm = sqrtf((sa + sb) * (1.0f / 16384.0f));
            float g = 1.0f / (1.0f + expf(-s1v * (rm - s2v)));
            garr[2 * t] = g;
            garr[2 * t + 1] = g;
        }
        for (int i = tid; i < NRI; i += 256) lsum[i] = 0.0f;
        __syncthreads();

        // ---------- phase h: h = (g o R) x W2 ; z = u_s - h (or out) ----------
        {
            float4 pr[2][6];
#pragma unroll
            for (int s = 0; s < 6; s++) pr[0][s] = w2[s * 256 + tid];
            {
                float4* db = (float4*)&wbuf[0][0];
#pragma unroll
                for (int s = 0; s < 6; s++) db[s * 256 + tid] = pr[0][s];
            }
#pragma unroll
            for (int s = 0; s < 6; s++) pr[1][s] = w2[1536 + s * 256 + tid];
            __syncthreads();

            floatx4 hacc[6];
#pragma unroll
            for (int nt = 0; nt < 6; nt++) hacc[nt] = (floatx4){0.f, 0.f, 0.f, 0.f};

#pragma unroll
            for (int ch = 0; ch < 8; ch++) {
                if (ch < 7) {
                    float4* db = (float4*)&wbuf[(ch + 1) % 3][0];
#pragma unroll
                    for (int s = 0; s < 6; s++) db[s * 256 + tid] = pr[(ch + 1) & 1][s];
                }
                if (ch < 6) {
#pragma unroll
                    for (int s = 0; s < 6; s++) pr[ch & 1][s] = w2[(ch + 2) * 1536 + s * 256 + tid];
                }
                __syncthreads();
                const f16* wb = &wbuf[ch % 3][0];
#pragma unroll
                for (int kc = 0; kc < 4; kc++) {
                    // transpose 2 R tiles (g-scaled) into wave-private LDS
#pragma unroll
                    for (int s2 = 0; s2 < 2; s2++) {
                        const int ti = ch * 8 + kc * 2 + s2;
                        float g = garr[ti * 16 + l15];
#pragma unroll
                        for (int r = 0; r < 4; r++)
                            trz[(s2 * 16 + l15) * 17 + quad * 4 + r] = g * R[ti][r];
                    }
                    half8 Ah, Al;
#pragma unroll
                    for (int j = 0; j < 8; j++) {
                        float v = trz[(quad * 8 + j) * 17 + l15];
                        f16 h = (f16)v;
                        Ah[j] = h;
                        Al[j] = (f16)(v - (float)h);
                    }
#pragma unroll
                    for (int nt = 0; nt < 6; nt++) {
                        half8 Bv = *(const half8*)(wb + ((kc * 6 + nt) * 64 + lane) * 8);
                        hacc[nt] = __builtin_amdgcn_mfma_f32_16x16x32_f16(Ah, Bv, hacc[nt], 0, 0, 0);
                        hacc[nt] = __builtin_amdgcn_mfma_f32_16x16x32_f16(Al, Bv, hacc[nt], 0, 0, 0);
                    }
                }
            }

            if (!last) {
#pragma unroll
                for (int nt = 0; nt < 6; nt++) {
#pragma unroll
                    for (int r = 0; r < 4; r++) {
                        float zv = usb[(wv * 16 + quad * 4 + r) * 96 + nt * 16 + l15] - hacc[nt][r];
                        trz[(nt * 16 + l15) * 17 + quad * 4 + r] = zv;
                    }
                }
            } else {
#pragma unroll
                for (int nt = 0; nt < 6; nt++) {
#pragma unroll
                    for (int r = 0; r < 4; r++) {
                        size_t gi = (size_t)(m0 + wv * 16 + quad * 4 + r) * 96 + nt * 16 + l15;
                        out[gi] = hacc[nt][r] * is;
                    }
                }
            }
            __syncthreads();   // wbuf reuse next layer
        }
    }
}

extern "C" void kernel_launch(void* const* d_in, const int* in_sizes, int n_in,
                              void* d_out, int out_size, void* d_ws, size_t ws_size,
                              hipStream_t stream) {
    const float* u  = (const float*)d_in[0];
    const float* S1 = (const float*)d_in[1];
    const float* S2 = (const float*)d_in[2];
    float* out = (float*)d_out;
    float* ws  = (float*)d_ws;
    int n = in_sizes[0];

    kmax<<<256, 256, 0, stream>>>(u, ws + OFF_PMAX, n);
    kinit<<<1, 256, 0, stream>>>(ws);
    kwf<<<768, 256, 0, stream>>>(ws);
    P<<<NBLK, 256, 0, stream>>>(u, ws, S1, S2, out);
}

// Round 6
// 2400.053 us; speedup vs baseline: 1.0688x; 1.0688x over previous
//
#include <hip/hip_runtime.h>
#include <math.h>

#define T 512
#define LAYERS 16
#define NBLK 256

typedef _Float16 f16;
typedef _Float16 half8 __attribute__((ext_vector_type(8)));
typedef float floatx4 __attribute__((ext_vector_type(4)));

// ws float offsets
#define OFF_PMAX 0
#define OFF_SCALE 256                      // [0]=5/max, [1]=max/5
#define OFF_BAR 260                        // 2 uints
#define OFF_SUMS 512                       // LAYERS*1024
#define OFF_W1H (OFF_SUMS + LAYERS*1024)   // 98304 f16 = 49152 floats
#define OFF_W2H (OFF_W1H + 49152)          // 98304 f16

__global__ void kmax(const float* __restrict__ u, float* __restrict__ pmax, int n) {
    __shared__ float sm[256];
    float m = -1e30f;
    for (int i = blockIdx.x * blockDim.x + threadIdx.x; i < n; i += gridDim.x * blockDim.x)
        m = fmaxf(m, u[i]);
    sm[threadIdx.x] = m;
    __syncthreads();
    for (int s = 128; s > 0; s >>= 1) {
        if (threadIdx.x < s) sm[threadIdx.x] = fmaxf(sm[threadIdx.x], sm[threadIdx.x + s]);
        __syncthreads();
    }
    if (threadIdx.x == 0) pmax[blockIdx.x] = sm[0];
}

__global__ void kinit(float* __restrict__ ws) {
    __shared__ float sm[256];
    int t = threadIdx.x;
    sm[t] = ws[OFF_PMAX + t];
    __syncthreads();
    for (int s = 128; s > 0; s >>= 1) {
        if (t < s) sm[t] = fmaxf(sm[t], sm[t + s]);
        __syncthreads();
    }
    if (t == 0) {
        float m = fabsf(sm[0]);
        ws[OFF_SCALE]     = 5.0f / m;
        ws[OFF_SCALE + 1] = m / 5.0f;
    }
    if (t < 2) ((unsigned*)(ws + OFF_BAR))[t] = 0u;
    for (int i = t; i < LAYERS * 1024; i += 256) ws[OFF_SUMS + i] = 0.0f;
}

// Weight tables, f16, 64-col (W1) / 64-k (W2) chunk frag-linear.
// W1 chunk c64 (16 chunks, 6144 f16): idx=(((c64*4+nt4)*3+kc)*64+lane)*8+j,
//   k=kc*32+(lane>>4)*8+j, n=c64*64+nt4*16+(lane&15).
// W2 chunk ch (16 chunks): idx=(((ch*2+kc)*6+nt)*64+lane)*8+j,
//   k=ch*64+kc*32+(lane>>4)*8+j, fc=nt*16+(lane&15).
__global__ void kwf(float* __restrict__ ws) {
    int idx = blockIdx.x * 256 + threadIdx.x;
    if (idx >= 2 * 98304) return;
    int which = idx >= 98304;
    int id = which ? idx - 98304 : idx;
    int j = id & 7, lane = (id >> 3) & 63, r = id >> 9;
    int quad = lane >> 4, l15 = lane & 15;
    int k, n, t, f, q, e;
    if (!which) {
        int kc = r % 3, r2 = r / 3, nt4 = r2 & 3, c64 = r2 >> 2;
        k = kc * 32 + quad * 8 + j;
        n = c64 * 64 + nt4 * 16 + l15;
        f = k >> 1; q = k & 1; t = n >> 1; e = n & 1;
    } else {
        int nt = r % 6, r2 = r / 6, kc = r2 & 1, ch = r2 >> 1;
        k = ch * 64 + kc * 32 + quad * 8 + j;
        n = nt * 16 + l15;
        t = k >> 1; q = k & 1; f = n >> 1; e = n & 1;
    }
    int ft = (f * t) & (T - 1);
    float sv, cv;
    sincosf((float)ft * 0.012271846303085129f, &sv, &cv);
    const float sc = 0.04419417382415922f;
    cv *= sc; sv *= sc;
    float val;
    if (!which) val = (e == 0) ? (q == 0 ? cv : -sv) : (q == 0 ?  sv : cv);
    else        val = (e == 0) ? (q == 0 ? cv :  sv) : (q == 0 ? -sv : cv);
    f16* dst = (f16*)(ws + (which ? OFF_W2H : OFF_W1H));
    dst[id] = (f16)val;
}

__device__ __forceinline__ void gridbar(unsigned* bar) {
    __syncthreads();
    if (threadIdx.x == 0) {
        unsigned gen = __hip_atomic_load(&bar[1], __ATOMIC_RELAXED, __HIP_MEMORY_SCOPE_AGENT);
        unsigned a = __hip_atomic_fetch_add(&bar[0], 1u, __ATOMIC_ACQ_REL, __HIP_MEMORY_SCOPE_AGENT);
        if (a + 1 == NBLK) {
            __hip_atomic_store(&bar[0], 0u, __ATOMIC_RELAXED, __HIP_MEMORY_SCOPE_AGENT);
            __hip_atomic_fetch_add(&bar[1], 1u, __ATOMIC_RELEASE, __HIP_MEMORY_SCOPE_AGENT);
        } else {
            while (__hip_atomic_load(&bar[1], __ATOMIC_ACQUIRE, __HIP_MEMORY_SCOPE_AGENT) == gen)
                __builtin_amdgcn_s_sleep(8);
        }
    }
    __syncthreads();
}

#define MFMA(a, b, c) __builtin_amdgcn_mfma_f32_16x16x32_f16((a), (b), (c), 0, 0, 0)

// Persistent: 256 blocks x 512 thr (8 waves). Wave = 32 rows (rp) x 256 cols (nq).
// R per lane: 2 rowgroups x 16 tiles x floatx4 = 128 VGPRs, register-resident 16 layers.
__global__ __launch_bounds__(512, 2) void P(const float* __restrict__ u, float* __restrict__ ws,
                                            const float* __restrict__ S1, const float* __restrict__ S2,
                                            float* __restrict__ out) {
    __shared__ f16 wbuf[2][24576];     // 96 KB double-buffered weight chunk-set
    __shared__ float zb[6208];         // 24.8 KB z tile [row][fc], stride 97
    __shared__ float garr[1024];       // gate
    __shared__ float lsum[1024];       // block |R|^2 partials
    __shared__ float trw[8][544];      // 17 KB per-wave transpose scratch (17-pad)

    const int tid = threadIdx.x;
    const int wv = tid >> 6;
    const int lane = tid & 63;
    const int quad = lane >> 4, l15 = lane & 15;
    const int rp = wv >> 2;            // 0..1: rows rp*32..+31
    const int nq = wv & 3;             // col quarter: n in [nq*256, +256)
    const int m0 = blockIdx.x * 64;
    float* __restrict__ trz = trw[wv];

    unsigned* bar = (unsigned*)(ws + OFF_BAR);
    float* __restrict__ sums = ws + OFF_SUMS;
    const float4* __restrict__ w1 = (const float4*)(ws + OFF_W1H);
    const float4* __restrict__ w2 = (const float4*)(ws + OFF_W2H);
    const float s5 = ws[OFF_SCALE], is = ws[OFF_SCALE + 1];
    const float s1v = S1[0], s2v = S2[0];

    const int slot = wv >> 1;          // staging: 2 waves per 12 KB chunk
    const int hf = wv & 1;
    const int soff = slot * 6144 + hf * 3072;   // f16 offset within buffer

    for (int i = tid; i < 6144; i += 512) {
        int row = i / 96, fc = i - row * 96;
        zb[row * 97 + fc] = s5 * u[(size_t)m0 * 96 + i];
    }
    for (int i = tid; i < 1024; i += 512) lsum[i] = 0.0f;
    __syncthreads();

    floatx4 R[2][16];

    for (int l = 0; l < LAYERS; l++) {
        const bool first = (l == 0), last = (l == LAYERS - 1);

        // ================= phase Z: R = g.R + z x W1 ; lsum =================
        {
            half8 Ah[2][3], Al[2][3];
#pragma unroll
            for (int rg = 0; rg < 2; rg++)
#pragma unroll
                for (int kc = 0; kc < 3; kc++)
#pragma unroll
                    for (int j = 0; j < 8; j++) {
                        float v = zb[(rp * 32 + rg * 16 + l15) * 97 + kc * 32 + quad * 8 + j];
                        f16 h = (f16)v;
                        Ah[rg][kc][j] = h;
                        Al[rg][kc][j] = (f16)(v - (float)h);
                    }
            float4 pr[6];
#pragma unroll
            for (int r = 0; r < 6; r++) pr[r] = w1[((slot * 4 + 0) * 6144 + hf * 3072 + r * 512 + lane * 8) >> 3];
            {
                float4* db = (float4*)&wbuf[0][0];
#pragma unroll
                for (int r = 0; r < 6; r++) db[(soff + r * 512 + lane * 8) >> 3] = pr[r];
            }
#pragma unroll
            for (int r = 0; r < 6; r++) pr[r] = w1[((slot * 4 + 1) * 6144 + hf * 3072 + r * 512 + lane * 8) >> 3];
            __syncthreads();
#pragma unroll
            for (int i = 0; i < 4; i++) {
                if (i < 3) {
                    float4* db = (float4*)&wbuf[(i + 1) & 1][0];
#pragma unroll
                    for (int r = 0; r < 6; r++) db[(soff + r * 512 + lane * 8) >> 3] = pr[r];
                }
                if (i < 2) {
#pragma unroll
                    for (int r = 0; r < 6; r++)
                        pr[r] = w1[((slot * 4 + i + 2) * 6144 + hf * 3072 + r * 512 + lane * 8) >> 3];
                }
                const f16* wb = &wbuf[i & 1][nq * 6144];
#pragma unroll
                for (int nt = 0; nt < 4; nt++) {
                    const int ti = i * 4 + nt;
#pragma unroll
                    for (int rg = 0; rg < 2; rg++) {
                        floatx4 acc;
                        if (first) acc = (floatx4){0.f, 0.f, 0.f, 0.f};
                        else { float g = garr[nq * 256 + ti * 16 + l15]; acc = g * R[rg][ti]; }
#pragma unroll
                        for (int kc = 0; kc < 3; kc++) {
                            half8 Bv = *(const half8*)(wb + ((nt * 3 + kc) * 64 + lane) * 8);
                            acc = MFMA(Ah[rg][kc], Bv, acc);
                            acc = MFMA(Al[rg][kc], Bv, acc);
                        }
                        R[rg][ti] = acc;
                        float cs = acc[0] * acc[0] + acc[1] * acc[1] + acc[2] * acc[2] + acc[3] * acc[3];
                        cs += __shfl_xor(cs, 16, 64);
                        cs += __shfl_xor(cs, 32, 64);
                        if (lane < 16) atomicAdd(&lsum[nq * 256 + ti * 16 + lane], cs);
                    }
                }
                __syncthreads();
            }
        }

        // ================= flush + grid barrier + gate + zb init =================
        for (int i = tid; i < 1024; i += 512) atomicAdd(&sums[l * 1024 + i], lsum[i]);
        __threadfence();
        gridbar(bar);
        {
            int t = tid;
            float sa = __hip_atomic_load(&sums[l * 1024 + 2 * t], __ATOMIC_RELAXED, __HIP_MEMORY_SCOPE_AGENT);
            float sb = __hip_atomic_load(&sums[l * 1024 + 2 * t + 1], __ATOMIC_RELAXED, __HIP_MEMORY_SCOPE_AGENT);
            float rm = sqrtf((sa + sb) * (1.0f / 16384.0f));
            float g = 1.0f / (1.0f + expf(-s1v * (rm - s2v)));
            garr[2 * t] = g;
            garr[2 * t + 1] = g;
        }
        for (int i = tid; i < 1024; i += 512) lsum[i] = 0.0f;
        if (!last) {
            for (int i = tid; i < 6144; i += 512) {
                int row = i / 96, fc = i - row * 96;
                zb[row * 97 + fc] = s5 * u[(size_t)m0 * 96 + i];
            }
        } else {
            for (int i = tid; i < 6208; i += 512) zb[i] = 0.0f;
        }
        __syncthreads();

        // ================= phase h: h = (g.R) x W2 ; zb -= h (or +=h for out) =================
        {
            float4 pr[6];
            floatx4 hacc[2][6];
#pragma unroll
            for (int rg = 0; rg < 2; rg++)
#pragma unroll
                for (int nt = 0; nt < 6; nt++) hacc[rg][nt] = (floatx4){0.f, 0.f, 0.f, 0.f};
#pragma unroll
            for (int r = 0; r < 6; r++) pr[r] = w2[((slot * 4 + 0) * 6144 + hf * 3072 + r * 512 + lane * 8) >> 3];
            {
                float4* db = (float4*)&wbuf[0][0];
#pragma unroll
                for (int r = 0; r < 6; r++) db[(soff + r * 512 + lane * 8) >> 3] = pr[r];
            }
#pragma unroll
            for (int r = 0; r < 6; r++) pr[r] = w2[((slot * 4 + 1) * 6144 + hf * 3072 + r * 512 + lane * 8) >> 3];
            __syncthreads();
#pragma unroll
            for (int i = 0; i < 4; i++) {
                if (i < 3) {
                    float4* db = (float4*)&wbuf[(i + 1) & 1][0];
#pragma unroll
                    for (int r = 0; r < 6; r++) db[(soff + r * 512 + lane * 8) >> 3] = pr[r];
                }
                if (i < 2) {
#pragma unroll
                    for (int r = 0; r < 6; r++)
                        pr[r] = w2[((slot * 4 + i + 2) * 6144 + hf * 3072 + r * 512 + lane * 8) >> 3];
                }
                const f16* wb = &wbuf[i & 1][nq * 6144];
#pragma unroll
                for (int kc = 0; kc < 2; kc++) {
#pragma unroll
                    for (int rg = 0; rg < 2; rg++) {
#pragma unroll
                        for (int s2 = 0; s2 < 2; s2++) {
                            const int ti = i * 4 + kc * 2 + s2;
                            float g = garr[nq * 256 + ti * 16 + l15];
#pragma unroll
                            for (int r = 0; r < 4; r++)
                                trz[(s2 * 16 + l15) * 17 + quad * 4 + r] = g * R[rg][ti][r];
                        }
                        half8 Ah, Al;
#pragma unroll
                        for (int j = 0; j < 8; j++) {
                            float v = trz[(quad * 8 + j) * 17 + l15];
                            f16 h = (f16)v;
                            Ah[j] = h;
                            Al[j] = (f16)(v - (float)h);
                        }
#pragma unroll
                        for (int nt = 0; nt < 6; nt++) {
                            half8 Bv = *(const half8*)(wb + ((kc * 6 + nt) * 64 + lane) * 8);
                            hacc[rg][nt] = MFMA(Ah, Bv, hacc[rg][nt]);
                            hacc[rg][nt] = MFMA(Al, Bv, hacc[rg][nt]);
                        }
                    }
                }
                __syncthreads();
            }

#pragma unroll
            for (int rg = 0; rg < 2; rg++)
#pragma unroll
                for (int nt = 0; nt < 6; nt++)
#pragma unroll
                    for (int r = 0; r < 4; r++) {
                        int row = rp * 32 + rg * 16 + quad * 4 + r;
                        int fc = nt * 16 + l15;
                        atomicAdd(&zb[row * 97 + fc], last ? hacc[rg][nt][r] : -hacc[rg][nt][r]);
                    }
            __syncthreads();
            if (last) {
                for (int i = tid; i < 6144; i += 512) {
                    int row = i / 96, fc = i - row * 96;
                    out[(size_t)m0 * 96 + i] = zb[row * 97 + fc] * is;
                }
            }
        }
    }
}

extern "C" void kernel_launch(void* const* d_in, const int* in_sizes, int n_in,
                              void* d_out, int out_size, void* d_ws, size_t ws_size,
                              hipStream_t stream) {
    const float* u  = (const float*)d_in[0];
    const float* S1 = (const float*)d_in[1];
    const float* S2 = (const float*)d_in[2];
    float* out = (float*)d_out;
    float* ws  = (float*)d_ws;
    int n = in_sizes[0];

    kmax<<<256, 256, 0, stream>>>(u, ws + OFF_PMAX, n);
    kinit<<<1, 256, 0, stream>>>(ws);
    kwf<<<768, 256, 0, stream>>>(ws);
    P<<<NBLK, 512, 0, stream>>>(u, ws, S1, S2, out);
}

// Round 7
// 2394.772 us; speedup vs baseline: 1.0711x; 1.0022x over previous
//
#include <hip/hip_runtime.h>
#include <math.h>

#define T 512
#define LAYERS 16
#define NBLK 256

typedef _Float16 f16;
typedef _Float16 half8 __attribute__((ext_vector_type(8)));
typedef float floatx4 __attribute__((ext_vector_type(4)));

// ws float offsets
#define OFF_PMAX 0
#define OFF_SCALE 256                      // [0]=5/max, [1]=max/5
#define OFF_BAR 260                        // 2 uints
#define OFF_SUMS 512                       // LAYERS*1024
#define OFF_W1H (OFF_SUMS + LAYERS*1024)   // 98304 f16 = 49152 floats
#define OFF_W2H (OFF_W1H + 49152)          // 98304 f16

__global__ void kmax(const float* __restrict__ u, float* __restrict__ pmax, int n) {
    __shared__ float sm[256];
    float m = -1e30f;
    for (int i = blockIdx.x * blockDim.x + threadIdx.x; i < n; i += gridDim.x * blockDim.x)
        m = fmaxf(m, u[i]);
    sm[threadIdx.x] = m;
    __syncthreads();
    for (int s = 128; s > 0; s >>= 1) {
        if (threadIdx.x < s) sm[threadIdx.x] = fmaxf(sm[threadIdx.x], sm[threadIdx.x + s]);
        __syncthreads();
    }
    if (threadIdx.x == 0) pmax[blockIdx.x] = sm[0];
}

__global__ void kinit(float* __restrict__ ws) {
    __shared__ float sm[256];
    int t = threadIdx.x;
    sm[t] = ws[OFF_PMAX + t];
    __syncthreads();
    for (int s = 128; s > 0; s >>= 1) {
        if (t < s) sm[t] = fmaxf(sm[t], sm[t + s]);
        __syncthreads();
    }
    if (t == 0) {
        float m = fabsf(sm[0]);
        ws[OFF_SCALE]     = 5.0f / m;
        ws[OFF_SCALE + 1] = m / 5.0f;
    }
    if (t < 2) ((unsigned*)(ws + OFF_BAR))[t] = 0u;
    for (int i = t; i < LAYERS * 1024; i += 256) ws[OFF_SUMS + i] = 0.0f;
}

// Weight tables, f16, 64-col (W1) / 64-k (W2) chunk frag-linear (R5-proven layout).
__global__ void kwf(float* __restrict__ ws) {
    int idx = blockIdx.x * 256 + threadIdx.x;
    if (idx >= 2 * 98304) return;
    int which = idx >= 98304;
    int id = which ? idx - 98304 : idx;
    int j = id & 7, lane = (id >> 3) & 63, r = id >> 9;
    int quad = lane >> 4, l15 = lane & 15;
    int k, n, t, f, q, e;
    if (!which) {
        int kc = r % 3, r2 = r / 3, nt4 = r2 & 3, c64 = r2 >> 2;
        k = kc * 32 + quad * 8 + j;
        n = c64 * 64 + nt4 * 16 + l15;
        f = k >> 1; q = k & 1; t = n >> 1; e = n & 1;
    } else {
        int nt = r % 6, r2 = r / 6, kc = r2 & 1, ch = r2 >> 1;
        k = ch * 64 + kc * 32 + quad * 8 + j;
        n = nt * 16 + l15;
        t = k >> 1; q = k & 1; f = n >> 1; e = n & 1;
    }
    int ft = (f * t) & (T - 1);
    float sv, cv;
    sincosf((float)ft * 0.012271846303085129f, &sv, &cv);
    const float sc = 0.04419417382415922f;
    cv *= sc; sv *= sc;
    float val;
    if (!which) val = (e == 0) ? (q == 0 ? cv : -sv) : (q == 0 ?  sv : cv);
    else        val = (e == 0) ? (q == 0 ? cv :  sv) : (q == 0 ? -sv : cv);
    f16* dst = (f16*)(ws + (which ? OFF_W2H : OFF_W1H));
    dst[id] = (f16)val;
}

__device__ __forceinline__ void gridbar(unsigned* bar) {
    __syncthreads();
    if (threadIdx.x == 0) {
        unsigned gen = __hip_atomic_load(&bar[1], __ATOMIC_RELAXED, __HIP_MEMORY_SCOPE_AGENT);
        unsigned a = __hip_atomic_fetch_add(&bar[0], 1u, __ATOMIC_ACQ_REL, __HIP_MEMORY_SCOPE_AGENT);
        if (a + 1 == NBLK) {
            __hip_atomic_store(&bar[0], 0u, __ATOMIC_RELAXED, __HIP_MEMORY_SCOPE_AGENT);
            __hip_atomic_fetch_add(&bar[1], 1u, __ATOMIC_RELEASE, __HIP_MEMORY_SCOPE_AGENT);
        } else {
            while (__hip_atomic_load(&bar[1], __ATOMIC_ACQUIRE, __HIP_MEMORY_SCOPE_AGENT) == gen)
                __builtin_amdgcn_s_sleep(8);
        }
    }
    __syncthreads();
}

__device__ __forceinline__ void stage16(const f16* g, f16* l) {
    __builtin_amdgcn_global_load_lds(
        (const __attribute__((address_space(1))) unsigned int*)g,
        (__attribute__((address_space(3))) unsigned int*)l, 16, 0, 0);
}

#define MFMA(a, b, c) __builtin_amdgcn_mfma_f32_16x16x32_f16((a), (b), (c), 0, 0, 0)

// Persistent: 256 blocks x 512 thr (8 waves, 2/SIMD). Wave = 32 rows (rp) x 256 cols (nq).
// R: 2 rowgroups x 16 tiles x floatx4 = 128 VGPRs/lane, register-resident for 16 layers.
// Weights stream via async global_load_lds (no VGPR relay). Phase h: rg-outer (hacc[6]).
__global__ __launch_bounds__(512, 2) void P(const float* __restrict__ u, float* __restrict__ ws,
                                            const float* __restrict__ S1, const float* __restrict__ S2,
                                            float* __restrict__ out) {
    __shared__ f16 wbuf[2][24576];     // 96 KB double-buffered weight chunk-set
    __shared__ float zb[6400];         // 25.6 KB z tile [row][fc], stride 100
    __shared__ float garr[1024];
    __shared__ float lsum[1024];
    __shared__ float trw[8][576];      // 18 KB per-wave transpose, stride 36 + rot swizzle

    const int tid = threadIdx.x;
    const int wv = tid >> 6;
    const int lane = tid & 63;
    const int quad = lane >> 4, l15 = lane & 15;
    const int rp = wv >> 2;            // row half
    const int nq = wv & 3;             // col quarter
    const int m0 = blockIdx.x * 64;
    float* __restrict__ trz = trw[wv];

    unsigned* bar = (unsigned*)(ws + OFF_BAR);
    float* __restrict__ sums = ws + OFF_SUMS;
    const f16* __restrict__ w1 = (const f16*)(ws + OFF_W1H);
    const f16* __restrict__ w2 = (const f16*)(ws + OFF_W2H);
    const float s5 = ws[OFF_SCALE], is = ws[OFF_SCALE + 1];
    const float s1v = S1[0], s2v = S2[0];

    const int slot = wv >> 1, hf = wv & 1;
    const int soff = slot * 6144 + hf * 3072;

    auto stageW = [&](const f16* W, int set, int buf) {
        const f16* g = W + (slot * 4 + set) * 6144 + hf * 3072 + lane * 8;
        f16* l = &wbuf[buf][soff];
#pragma unroll
        for (int r = 0; r < 6; r++) stage16(g + r * 512, l + r * 512);
    };

    for (int i = tid; i < 6144; i += 512) {
        int row = i / 96, fc = i - row * 96;
        zb[row * 100 + fc] = s5 * u[(size_t)m0 * 96 + i];
    }
    for (int i = tid; i < 1024; i += 512) lsum[i] = 0.0f;
    __syncthreads();

    floatx4 R[2][16];

    for (int l = 0; l < LAYERS; l++) {
        const bool first = (l == 0), last = (l == LAYERS - 1);

        // ================= phase Z: R = g.R + z x W1 ; lsum =================
        {
            half8 Ah[2][3], Al[2][3];
#pragma unroll
            for (int rg = 0; rg < 2; rg++)
#pragma unroll
                for (int kc = 0; kc < 3; kc++)
#pragma unroll
                    for (int j = 0; j < 8; j++) {
                        float v = zb[(rp * 32 + rg * 16 + l15) * 100 + kc * 32 + quad * 8 + j];
                        f16 h = (f16)v;
                        Ah[rg][kc][j] = h;
                        Al[rg][kc][j] = (f16)(v - (float)h);
                    }
            stageW(w1, 0, 0);
            __syncthreads();
            stageW(w1, 1, 1);
#pragma unroll
            for (int i = 0; i < 4; i++) {
                const f16* wb = &wbuf[i & 1][nq * 6144];
#pragma unroll
                for (int nt = 0; nt < 4; nt++) {
                    const int ti = i * 4 + nt;
#pragma unroll
                    for (int rg = 0; rg < 2; rg++) {
                        floatx4 acc;
                        if (first) acc = (floatx4){0.f, 0.f, 0.f, 0.f};
                        else { float g = garr[nq * 256 + ti * 16 + l15]; acc = g * R[rg][ti]; }
#pragma unroll
                        for (int kc = 0; kc < 3; kc++) {
                            half8 Bv = *(const half8*)(wb + ((nt * 3 + kc) * 64 + lane) * 8);
                            acc = MFMA(Ah[rg][kc], Bv, acc);
                            acc = MFMA(Al[rg][kc], Bv, acc);
                        }
                        R[rg][ti] = acc;
                        float cs = acc[0] * acc[0] + acc[1] * acc[1] + acc[2] * acc[2] + acc[3] * acc[3];
                        cs += __shfl_xor(cs, 16, 64);
                        cs += __shfl_xor(cs, 32, 64);
                        if (lane < 16) atomicAdd(&lsum[nq * 256 + ti * 16 + lane], cs);
                    }
                }
                __syncthreads();
                if (i < 2) stageW(w1, i + 2, i & 1);
            }
        }

        // ================= flush + grid barrier + gate + zb refill =================
        for (int i = tid; i < 1024; i += 512) atomicAdd(&sums[l * 1024 + i], lsum[i]);
        __threadfence();
        gridbar(bar);
        {
            int t = tid;
            float sa = __hip_atomic_load(&sums[l * 1024 + 2 * t], __ATOMIC_RELAXED, __HIP_MEMORY_SCOPE_AGENT);
            float sb = __hip_atomic_load(&sums[l * 1024 + 2 * t + 1], __ATOMIC_RELAXED, __HIP_MEMORY_SCOPE_AGENT);
            float rm = sqrtf((sa + sb) * (1.0f / 16384.0f));
            float g = 1.0f / (1.0f + expf(-s1v * (rm - s2v)));
            garr[2 * t] = g;
            garr[2 * t + 1] = g;
        }
        for (int i = tid; i < 1024; i += 512) lsum[i] = 0.0f;
        if (!last) {
            for (int i = tid; i < 6144; i += 512) {
                int row = i / 96, fc = i - row * 96;
                zb[row * 100 + fc] = s5 * u[(size_t)m0 * 96 + i];
            }
        } else {
            for (int i = tid; i < 6400; i += 512) zb[i] = 0.0f;
        }
        __syncthreads();

        // ================= phase h (rg-outer): h = (g.R) x W2 ; zb -=/+= h =================
#pragma unroll 1
        for (int rg = 0; rg < 2; rg++) {
            floatx4 hacc[6];
#pragma unroll
            for (int nt = 0; nt < 6; nt++) hacc[nt] = (floatx4){0.f, 0.f, 0.f, 0.f};
            stageW(w2, 0, 0);
            __syncthreads();
            stageW(w2, 1, 1);
#pragma unroll
            for (int i = 0; i < 4; i++) {
                const f16* wb = &wbuf[i & 1][nq * 6144];
#pragma unroll
                for (int kc = 0; kc < 2; kc++) {
                    // transpose 2 R tiles into Tr[b=row 0..15][a=k 0..31], phys=b*36+((a+8*(b>>2))&31)
#pragma unroll
                    for (int s2 = 0; s2 < 2; s2++) {
                        const int ti = i * 4 + kc * 2 + s2;
                        float g = garr[nq * 256 + ti * 16 + l15];
#pragma unroll
                        for (int r = 0; r < 4; r++)
                            trz[(quad * 4 + r) * 36 + ((s2 * 16 + l15 + 8 * quad) & 31)] = g * R[rg][ti][r];
                    }
                    const int rbase = l15 * 36 + ((8 * quad + 8 * (l15 >> 2)) & 31);
                    float4 v0 = *(const float4*)&trz[rbase];
                    float4 v1 = *(const float4*)&trz[rbase + 4];
                    float vv[8] = {v0.x, v0.y, v0.z, v0.w, v1.x, v1.y, v1.z, v1.w};
                    half8 Ah, Al;
#pragma unroll
                    for (int j = 0; j < 8; j++) {
                        f16 h = (f16)vv[j];
                        Ah[j] = h;
                        Al[j] = (f16)(vv[j] - (float)h);
                    }
#pragma unroll
                    for (int nt = 0; nt < 6; nt++) {
                        half8 Bv = *(const half8*)(wb + ((kc * 6 + nt) * 64 + lane) * 8);
                        hacc[nt] = MFMA(Ah, Bv, hacc[nt]);
                        hacc[nt] = MFMA(Al, Bv, hacc[nt]);
                    }
                }
                __syncthreads();
                if (i < 2) stageW(w2, i + 2, i & 1);
            }
#pragma unroll
            for (int nt = 0; nt < 6; nt++)
#pragma unroll
                for (int r = 0; r < 4; r++) {
                    int row = rp * 32 + rg * 16 + quad * 4 + r;
                    atomicAdd(&zb[row * 100 + nt * 16 + l15], last ? hacc[nt][r] : -hacc[nt][r]);
                }
        }
        __syncthreads();
        if (last) {
            for (int i = tid; i < 6144; i += 512) {
                int row = i / 96, fc = i - row * 96;
                out[(size_t)m0 * 96 + i] = zb[row * 100 + fc] * is;
            }
        }
    }
}

extern "C" void kernel_launch(void* const* d_in, const int* in_sizes, int n_in,
                              void* d_out, int out_size, void* d_ws, size_t ws_size,
                              hipStream_t stream) {
    const float* u  = (const float*)d_in[0];
    const float* S1 = (const float*)d_in[1];
    const float* S2 = (const float*)d_in[2];
    float* out = (float*)d_out;
    float* ws  = (float*)d_ws;
    int n = in_sizes[0];

    kmax<<<256, 256, 0, stream>>>(u, ws + OFF_PMAX, n);
    kinit<<<1, 256, 0, stream>>>(ws);
    kwf<<<768, 256, 0, stream>>>(ws);
    P<<<NBLK, 512, 0, stream>>>(u, ws, S1, S2, out);
}

// Round 8
// 2042.144 us; speedup vs baseline: 1.2561x; 1.1727x over previous
//
#include <hip/hip_runtime.h>
#include <math.h>

#define T 512
#define LAYERS 16
#define NBLK 256

typedef _Float16 f16;
typedef _Float16 half8 __attribute__((ext_vector_type(8)));
typedef float floatx4 __attribute__((ext_vector_type(4)));

// ws float offsets
#define OFF_PMAX 0
#define OFF_SCALE 256                      // [0]=5/max, [1]=max/5
#define OFF_BAR 260                        // 2 uints
#define OFF_SUMS 512                       // LAYERS*1024
#define OFF_W1H (OFF_SUMS + LAYERS*1024)   // 98304 f16 = 49152 floats
#define OFF_W2H (OFF_W1H + 49152)          // 98304 f16

__global__ void kmax(const float* __restrict__ u, float* __restrict__ pmax, int n) {
    __shared__ float sm[256];
    float m = -1e30f;
    for (int i = blockIdx.x * blockDim.x + threadIdx.x; i < n; i += gridDim.x * blockDim.x)
        m = fmaxf(m, u[i]);
    sm[threadIdx.x] = m;
    __syncthreads();
    for (int s = 128; s > 0; s >>= 1) {
        if (threadIdx.x < s) sm[threadIdx.x] = fmaxf(sm[threadIdx.x], sm[threadIdx.x + s]);
        __syncthreads();
    }
    if (threadIdx.x == 0) pmax[blockIdx.x] = sm[0];
}

__global__ void kinit(float* __restrict__ ws) {
    __shared__ float sm[256];
    int t = threadIdx.x;
    sm[t] = ws[OFF_PMAX + t];
    __syncthreads();
    for (int s = 128; s > 0; s >>= 1) {
        if (t < s) sm[t] = fmaxf(sm[t], sm[t + s]);
        __syncthreads();
    }
    if (t == 0) {
        float m = fabsf(sm[0]);
        ws[OFF_SCALE]     = 5.0f / m;
        ws[OFF_SCALE + 1] = m / 5.0f;
    }
    if (t < 2) ((unsigned*)(ws + OFF_BAR))[t] = 0u;
    for (int i = t; i < LAYERS * 1024; i += 256) ws[OFF_SUMS + i] = 0.0f;
}

// Weight tables, f16, 64-col (W1) / 64-k (W2) chunk frag-linear (R5/R6-proven layout).
__global__ void kwf(float* __restrict__ ws) {
    int idx = blockIdx.x * 256 + threadIdx.x;
    if (idx >= 2 * 98304) return;
    int which = idx >= 98304;
    int id = which ? idx - 98304 : idx;
    int j = id & 7, lane = (id >> 3) & 63, r = id >> 9;
    int quad = lane >> 4, l15 = lane & 15;
    int k, n, t, f, q, e;
    if (!which) {
        int kc = r % 3, r2 = r / 3, nt4 = r2 & 3, c64 = r2 >> 2;
        k = kc * 32 + quad * 8 + j;
        n = c64 * 64 + nt4 * 16 + l15;
        f = k >> 1; q = k & 1; t = n >> 1; e = n & 1;
    } else {
        int nt = r % 6, r2 = r / 6, kc = r2 & 1, ch = r2 >> 1;
        k = ch * 64 + kc * 32 + quad * 8 + j;
        n = nt * 16 + l15;
        t = k >> 1; q = k & 1; f = n >> 1; e = n & 1;
    }
    int ft = (f * t) & (T - 1);
    float sv, cv;
    sincosf((float)ft * 0.012271846303085129f, &sv, &cv);
    const float sc = 0.04419417382415922f;
    cv *= sc; sv *= sc;
    float val;
    if (!which) val = (e == 0) ? (q == 0 ? cv : -sv) : (q == 0 ?  sv : cv);
    else        val = (e == 0) ? (q == 0 ? cv :  sv) : (q == 0 ? -sv : cv);
    f16* dst = (f16*)(ws + (which ? OFF_W2H : OFF_W1H));
    dst[id] = (f16)val;
}

__device__ __forceinline__ void gridbar(unsigned* bar) {
    __syncthreads();
    if (threadIdx.x == 0) {
        unsigned gen = __hip_atomic_load(&bar[1], __ATOMIC_RELAXED, __HIP_MEMORY_SCOPE_AGENT);
        unsigned a = __hip_atomic_fetch_add(&bar[0], 1u, __ATOMIC_ACQ_REL, __HIP_MEMORY_SCOPE_AGENT);
        if (a + 1 == NBLK) {
            __hip_atomic_store(&bar[0], 0u, __ATOMIC_RELAXED, __HIP_MEMORY_SCOPE_AGENT);
            __hip_atomic_fetch_add(&bar[1], 1u, __ATOMIC_RELEASE, __HIP_MEMORY_SCOPE_AGENT);
        } else {
            while (__hip_atomic_load(&bar[1], __ATOMIC_ACQUIRE, __HIP_MEMORY_SCOPE_AGENT) == gen)
                __builtin_amdgcn_s_sleep(8);
        }
    }
    __syncthreads();
}

__device__ __forceinline__ void stage16(const f16* g, f16* l) {
    __builtin_amdgcn_global_load_lds(
        (const __attribute__((address_space(1))) unsigned int*)g,
        (__attribute__((address_space(3))) unsigned int*)l, 16, 0, 0);
}

#define MFMA(a, b, c) __builtin_amdgcn_mfma_f32_16x16x32_f16((a), (b), (c), 0, 0, 0)

// Persistent: 256 blocks x 512 thr (8 waves, pinned 2/SIMD -> 256 VGPR/lane budget).
// Wave = 32 rows (rp) x 256 cols (nq). R: 2x16 floatx4 = 128 VGPRs, register-resident.
// ALL R indices compile-time (every loop touching R fully unrolled) — no scratch.
__global__ __launch_bounds__(512, 2) __attribute__((amdgpu_waves_per_eu(2, 2)))
void P(const float* __restrict__ u, float* __restrict__ ws,
       const float* __restrict__ S1, const float* __restrict__ S2,
       float* __restrict__ out) {
    __shared__ f16 wbuf[2][24576];     // 96 KB double-buffered weight chunk-set
    __shared__ float zb[6400];         // 25.6 KB z tile [row][fc], stride 100
    __shared__ float garr[1024];
    __shared__ float lsum[1024];
    __shared__ float trw[8][576];      // per-wave transpose, stride 36 + rot swizzle

    const int tid = threadIdx.x;
    const int wv = tid >> 6;
    const int lane = tid & 63;
    const int quad = lane >> 4, l15 = lane & 15;
    const int rp = wv >> 2;            // row half
    const int nq = wv & 3;             // col quarter
    const int m0 = blockIdx.x * 64;
    float* __restrict__ trz = trw[wv];

    unsigned* bar = (unsigned*)(ws + OFF_BAR);
    float* __restrict__ sums = ws + OFF_SUMS;
    const f16* __restrict__ w1 = (const f16*)(ws + OFF_W1H);
    const f16* __restrict__ w2 = (const f16*)(ws + OFF_W2H);
    const float s5 = ws[OFF_SCALE], is = ws[OFF_SCALE + 1];
    const float s1v = S1[0], s2v = S2[0];

    const int slot = wv >> 1, hf = wv & 1;
    const int soff = slot * 6144 + hf * 3072;

    auto stageW = [&](const f16* W, int set, int buf) {
        const f16* g = W + (slot * 4 + set) * 6144 + hf * 3072 + lane * 8;
        f16* l = &wbuf[buf][soff];
#pragma unroll
        for (int r = 0; r < 6; r++) stage16(g + r * 512, l + r * 512);
    };

    for (int i = tid; i < 6144; i += 512) {
        int row = i / 96, fc = i - row * 96;
        zb[row * 100 + fc] = s5 * u[(size_t)m0 * 96 + i];
    }
    for (int i = tid; i < 1024; i += 512) { lsum[i] = 0.0f; garr[i] = 0.0f; }
    __syncthreads();

    floatx4 R[2][16];
#pragma unroll
    for (int rg = 0; rg < 2; rg++)
#pragma unroll
        for (int ti = 0; ti < 16; ti++) R[rg][ti] = (floatx4){0.f, 0.f, 0.f, 0.f};

    for (int l = 0; l < LAYERS; l++) {
        const bool last = (l == LAYERS - 1);

        // ================= phase Z: R = g.R + z x W1 ; lsum =================
        {
            half8 Ah[2][3], Al[2][3];
#pragma unroll
            for (int rg = 0; rg < 2; rg++)
#pragma unroll
                for (int kc = 0; kc < 3; kc++)
#pragma unroll
                    for (int j = 0; j < 8; j++) {
                        float v = zb[(rp * 32 + rg * 16 + l15) * 100 + kc * 32 + quad * 8 + j];
                        f16 h = (f16)v;
                        Ah[rg][kc][j] = h;
                        Al[rg][kc][j] = (f16)(v - (float)h);
                    }
            stageW(w1, 0, 0);
            __syncthreads();
            stageW(w1, 1, 1);
#pragma unroll
            for (int i = 0; i < 4; i++) {
                const f16* wb = &wbuf[i & 1][nq * 6144];
#pragma unroll
                for (int nt = 0; nt < 4; nt++) {
                    const int ti = i * 4 + nt;
#pragma unroll
                    for (int rg = 0; rg < 2; rg++) {
                        float g = garr[nq * 256 + ti * 16 + l15];
                        floatx4 acc = g * R[rg][ti];
#pragma unroll
                        for (int kc = 0; kc < 3; kc++) {
                            half8 Bv = *(const half8*)(wb + ((nt * 3 + kc) * 64 + lane) * 8);
                            acc = MFMA(Ah[rg][kc], Bv, acc);
                            acc = MFMA(Al[rg][kc], Bv, acc);
                        }
                        R[rg][ti] = acc;
                        float cs = acc[0] * acc[0] + acc[1] * acc[1] + acc[2] * acc[2] + acc[3] * acc[3];
                        cs += __shfl_xor(cs, 16, 64);
                        cs += __shfl_xor(cs, 32, 64);
                        if (lane < 16) atomicAdd(&lsum[nq * 256 + ti * 16 + lane], cs);
                    }
                }
                __syncthreads();
                if (i < 2) stageW(w1, i + 2, i & 1);
            }
        }

        // ================= flush + grid barrier + gate + zb refill =================
        for (int i = tid; i < 1024; i += 512) atomicAdd(&sums[l * 1024 + i], lsum[i]);
        __threadfence();
        gridbar(bar);
        {
            int t = tid;
            float sa = __hip_atomic_load(&sums[l * 1024 + 2 * t], __ATOMIC_RELAXED, __HIP_MEMORY_SCOPE_AGENT);
            float sb = __hip_atomic_load(&sums[l * 1024 + 2 * t + 1], __ATOMIC_RELAXED, __HIP_MEMORY_SCOPE_AGENT);
            float rm = sqrtf((sa + sb) * (1.0f / 16384.0f));
            float g = 1.0f / (1.0f + expf(-s1v * (rm - s2v)));
            garr[2 * t] = g;
            garr[2 * t + 1] = g;
        }
        for (int i = tid; i < 1024; i += 512) lsum[i] = 0.0f;
        if (!last) {
            for (int i = tid; i < 6144; i += 512) {
                int row = i / 96, fc = i - row * 96;
                zb[row * 100 + fc] = s5 * u[(size_t)m0 * 96 + i];
            }
        } else {
            for (int i = tid; i < 6400; i += 512) zb[i] = 0.0f;
        }
        __syncthreads();

        // ====== phase h (rg fully unrolled, hacc[6] reused): h = (g.R) x W2 ; zb -=/+= h ======
#pragma unroll
        for (int rg = 0; rg < 2; rg++) {
            floatx4 hacc[6];
#pragma unroll
            for (int nt = 0; nt < 6; nt++) hacc[nt] = (floatx4){0.f, 0.f, 0.f, 0.f};
            stageW(w2, 0, 0);
            __syncthreads();
            stageW(w2, 1, 1);
#pragma unroll
            for (int i = 0; i < 4; i++) {
                const f16* wb = &wbuf[i & 1][nq * 6144];
#pragma unroll
                for (int kc = 0; kc < 2; kc++) {
                    // transpose 2 R tiles: Tr[b=row16][a=k32], phys = b*36 + ((a + 8*(b>>2)) & 31)
#pragma unroll
                    for (int s2 = 0; s2 < 2; s2++) {
                        const int ti = i * 4 + kc * 2 + s2;
                        float g = garr[nq * 256 + ti * 16 + l15];
#pragma unroll
                        for (int r = 0; r < 4; r++)
                            trz[(quad * 4 + r) * 36 + ((s2 * 16 + l15 + 8 * quad) & 31)] = g * R[rg][ti][r];
                    }
                    const int rbase = l15 * 36 + ((8 * quad + 8 * (l15 >> 2)) & 31);
                    float4 v0 = *(const float4*)&trz[rbase];
                    float4 v1 = *(const float4*)&trz[rbase + 4];
                    float vv[8] = {v0.x, v0.y, v0.z, v0.w, v1.x, v1.y, v1.z, v1.w};
                    half8 Ah, Al;
#pragma unroll
                    for (int j = 0; j < 8; j++) {
                        f16 h = (f16)vv[j];
                        Ah[j] = h;
                        Al[j] = (f16)(vv[j] - (float)h);
                    }
#pragma unroll
                    for (int nt = 0; nt < 6; nt++) {
                        half8 Bv = *(const half8*)(wb + ((kc * 6 + nt) * 64 + lane) * 8);
                        hacc[nt] = MFMA(Ah, Bv, hacc[nt]);
                        hacc[nt] = MFMA(Al, Bv, hacc[nt]);
                    }
                }
                __syncthreads();
                if (i < 2) stageW(w2, i + 2, i & 1);
            }
#pragma unroll
            for (int nt = 0; nt < 6; nt++)
#pragma unroll
                for (int r = 0; r < 4; r++) {
                    int row = rp * 32 + rg * 16 + quad * 4 + r;
                    atomicAdd(&zb[row * 100 + nt * 16 + l15], last ? hacc[nt][r] : -hacc[nt][r]);
                }
        }
        __syncthreads();
        if (last) {
            for (int i = tid; i < 6144; i += 512) {
                int row = i / 96, fc = i - row * 96;
                out[(size_t)m0 * 96 + i] = zb[row * 100 + fc] * is;
            }
        }
    }
}

extern "C" void kernel_launch(void* const* d_in, const int* in_sizes, int n_in,
                              void* d_out, int out_size, void* d_ws, size_t ws_size,
                              hipStream_t stream) {
    const float* u  = (const float*)d_in[0];
    const float* S1 = (const float*)d_in[1];
    const float* S2 = (const float*)d_in[2];
    float* out = (float*)d_out;
    float* ws  = (float*)d_ws;
    int n = in_sizes[0];

    kmax<<<256, 256, 0, stream>>>(u, ws + OFF_PMAX, n);
    kinit<<<1, 256, 0, stream>>>(ws);
    kwf<<<768, 256, 0, stream>>>(ws);
    P<<<NBLK, 512, 0, stream>>>(u, ws, S1, S2, out);
}